// Round 5
// baseline (232.785 us; speedup 1.0000x reference)
//
#include <hip/hip_runtime.h>

// Sparsemax over last dim, rows of N=512 fp32 (65536 rows).
// Persistent grid-stride waves, 2 rows (1 pair) solved concurrently per step,
// 4 pairs per wave, SOFTWARE-PIPELINED: loads for pair p+1 are issued before
// solving pair p, hiding HBM latency under the Newton solve (rounds 2-4
// showed the kernel is load-latency-bound, not VALU- or BW-bound).
// tau via Newton on f(tau)=sum(max(z-tau,0))-1 warm-started at rowmax-1
// (support ~5-8 elems on Gaussian data -> ~3-4 iterations).

#define ROW_N 512
#define LANES 64
#define EPL 8  // elements per lane per row

#define DPP_ADD_STEP(v, ctrl, rmask)                                        \
  v += __int_as_float(__builtin_amdgcn_update_dpp(                          \
      0, __float_as_int(v), ctrl, rmask, 0xf, true))

#define DPP_MAX_STEP(v, ctrl, rmask)                                        \
  v = fmaxf(v, __int_as_float(__builtin_amdgcn_update_dpp(                  \
             __float_as_int(v), __float_as_int(v), ctrl, rmask, 0xf, false)))

// Two independent 64-lane reductions, chains interleaved for ILP.
__device__ inline void wave_sum64_x2(float& u, float& v) {
  DPP_ADD_STEP(u, 0x111, 0xf); DPP_ADD_STEP(v, 0x111, 0xf);
  DPP_ADD_STEP(u, 0x112, 0xf); DPP_ADD_STEP(v, 0x112, 0xf);
  DPP_ADD_STEP(u, 0x114, 0xf); DPP_ADD_STEP(v, 0x114, 0xf);
  DPP_ADD_STEP(u, 0x118, 0xf); DPP_ADD_STEP(v, 0x118, 0xf);
  DPP_ADD_STEP(u, 0x142, 0xa); DPP_ADD_STEP(v, 0x142, 0xa);
  DPP_ADD_STEP(u, 0x143, 0xc); DPP_ADD_STEP(v, 0x143, 0xc);
  u = __int_as_float(__builtin_amdgcn_readlane(__float_as_int(u), 63));
  v = __int_as_float(__builtin_amdgcn_readlane(__float_as_int(v), 63));
}

__device__ inline void wave_max64_x2(float& u, float& v) {
  DPP_MAX_STEP(u, 0x111, 0xf); DPP_MAX_STEP(v, 0x111, 0xf);
  DPP_MAX_STEP(u, 0x112, 0xf); DPP_MAX_STEP(v, 0x112, 0xf);
  DPP_MAX_STEP(u, 0x114, 0xf); DPP_MAX_STEP(v, 0x114, 0xf);
  DPP_MAX_STEP(u, 0x118, 0xf); DPP_MAX_STEP(v, 0x118, 0xf);
  DPP_MAX_STEP(u, 0x142, 0xa); DPP_MAX_STEP(v, 0x142, 0xa);
  DPP_MAX_STEP(u, 0x143, 0xc); DPP_MAX_STEP(v, 0x143, 0xc);
  u = __int_as_float(__builtin_amdgcn_readlane(__float_as_int(u), 63));
  v = __int_as_float(__builtin_amdgcn_readlane(__float_as_int(v), 63));
}

// Solve both rows of a pair; z arrays are the 8 per-lane elements of each row.
__device__ inline void solve_pair_x2(const float z0[EPL], const float z1[EPL],
                                     float& tau0, float& tau1) {
  float m0 = fmaxf(fmaxf(fmaxf(z0[0], z0[1]), fmaxf(z0[2], z0[3])),
                   fmaxf(fmaxf(z0[4], z0[5]), fmaxf(z0[6], z0[7])));
  float m1 = fmaxf(fmaxf(fmaxf(z1[0], z1[1]), fmaxf(z1[2], z1[3])),
                   fmaxf(fmaxf(z1[4], z1[5]), fmaxf(z1[6], z1[7])));
  wave_max64_x2(m0, m1);
  // tau* in [m-1, m): f(m-1) >= 0 since the max element alone contributes 1.
  tau0 = m0 - 1.0f;
  tau1 = m1 - 1.0f;
  int prev0 = -1, prev1 = -1;
  for (int iter = 0; iter < 16; ++iter) {
    float t0[EPL], t1[EPL];
    int k0 = 0, k1 = 0;
#pragma unroll
    for (int i = 0; i < EPL; ++i) {
      bool g0 = z0[i] > tau0;
      bool g1 = z1[i] > tau1;
      t0[i] = g0 ? z0[i] : 0.0f;
      t1[i] = g1 ? z1[i] : 0.0f;
      k0 += (int)__popcll(__ballot(g0));  // scalar pipe
      k1 += (int)__popcll(__ballot(g1));
    }
    float ls0 = ((t0[0] + t0[1]) + (t0[2] + t0[3])) +
                ((t0[4] + t0[5]) + (t0[6] + t0[7]));
    float ls1 = ((t1[0] + t1[1]) + (t1[2] + t1[3])) +
                ((t1[4] + t1[5]) + (t1[6] + t1[7]));
    wave_sum64_x2(ls0, ls1);
    tau0 = (ls0 - 1.0f) * __builtin_amdgcn_rcpf((float)k0);
    tau1 = (ls1 - 1.0f) * __builtin_amdgcn_rcpf((float)k1);
    // Support shrinks monotonically; equal count => equal set => fixed point.
    if (k0 == prev0 && k1 == prev1) break;
    prev0 = k0; prev1 = k1;
  }
}

__global__ __launch_bounds__(256) void sparsemax_kernel(
    const float* __restrict__ x, float* __restrict__ out, int npairs) {
  const int lane = threadIdx.x & 63;
  const int wid = (int)((blockIdx.x * blockDim.x + threadIdx.x) >> 6);
  const int nwaves = (int)((gridDim.x * blockDim.x) >> 6);

  int pp = wid;
  if (pp >= npairs) return;

  // Prologue: load pair `pp` (one pair = 2 contiguous rows = 256 float4).
  const float4* pc = (const float4*)(x + (size_t)pp * 2 * ROW_N);
  float4 ca0 = pc[lane], cb0 = pc[lane + 64];
  float4 ca1 = pc[lane + 128], cb1 = pc[lane + 192];

  while (true) {
    const int np = pp + nwaves;
    const bool have_next = np < npairs;
    float4 na0, nb0, na1, nb1;
    if (have_next) {  // issue next pair's loads BEFORE consuming current
      const float4* pn = (const float4*)(x + (size_t)np * 2 * ROW_N);
      na0 = pn[lane]; nb0 = pn[lane + 64];
      na1 = pn[lane + 128]; nb1 = pn[lane + 192];
    }

    float z0[EPL] = {ca0.x, ca0.y, ca0.z, ca0.w, cb0.x, cb0.y, cb0.z, cb0.w};
    float z1[EPL] = {ca1.x, ca1.y, ca1.z, ca1.w, cb1.x, cb1.y, cb1.z, cb1.w};
    float tau0, tau1;
    solve_pair_x2(z0, z1, tau0, tau1);

    float4* po = (float4*)(out + (size_t)pp * 2 * ROW_N);
    po[lane] = {fmaxf(z0[0] - tau0, 0.0f), fmaxf(z0[1] - tau0, 0.0f),
                fmaxf(z0[2] - tau0, 0.0f), fmaxf(z0[3] - tau0, 0.0f)};
    po[lane + 64] = {fmaxf(z0[4] - tau0, 0.0f), fmaxf(z0[5] - tau0, 0.0f),
                     fmaxf(z0[6] - tau0, 0.0f), fmaxf(z0[7] - tau0, 0.0f)};
    po[lane + 128] = {fmaxf(z1[0] - tau1, 0.0f), fmaxf(z1[1] - tau1, 0.0f),
                      fmaxf(z1[2] - tau1, 0.0f), fmaxf(z1[3] - tau1, 0.0f)};
    po[lane + 192] = {fmaxf(z1[4] - tau1, 0.0f), fmaxf(z1[5] - tau1, 0.0f),
                      fmaxf(z1[6] - tau1, 0.0f), fmaxf(z1[7] - tau1, 0.0f)};

    if (!have_next) break;
    ca0 = na0; cb0 = nb0; ca1 = na1; cb1 = nb1;
    pp = np;
  }
}

extern "C" void kernel_launch(void* const* d_in, const int* in_sizes, int n_in,
                              void* d_out, int out_size, void* d_ws,
                              size_t ws_size, hipStream_t stream) {
  const float* x = (const float*)d_in[0];
  float* out = (float*)d_out;
  const int nrows = in_sizes[0] / ROW_N;  // 65536 (even)
  const int npairs = nrows / 2;           // 32768
  // 2048 blocks x 4 waves = 8192 waves; 4 pairs/wave, uniform trip count.
  sparsemax_kernel<<<2048, 256, 0, stream>>>(x, out, npairs);
}